// Round 7
// baseline (407.830 us; speedup 1.0000x reference)
//
#include <hip/hip_runtime.h>

// GCN forward, CSR-gather formulation, round 7.
// CSR build via 2-level counting sort: bin edges into 8 dst-range buckets
// (packed 31-bit codes), then per-bucket count + place with L2-resident
// working sets. fp16 gather tables, 8-aligned padded adjacency lists,
// LDS-deduped pool atomics.

#define N_NODES 100000
#define N_EDGES 3200000
#define N_GRAPHS 1024
#define IN_F 6
#define SXS 8
#define H1 64
#define H2 32
#define SLOPE 0.01f

#define SCAN_BLK 1024
#define SCAN_NB ((N_NODES + SCAN_BLK - 1) / SCAN_BLK)   // 98
#define CSR_CAP 4000000                                 // >= E + 7N

#define NB 8                 // dst-range buckets (== XCDs)
#define BROW 12500           // nodes per bucket
#define BCAP 408000          // per-bucket edge capacity (E/8=400k avg, 13sigma pad)
#define BIN_SEG 4096         // edges per k_bin block
#define E4 (N_EDGES / 4)

typedef _Float16 f16;

static __device__ __forceinline__ float lrelu(float v) {
    return v > 0.0f ? v : SLOPE * v;
}

// ---- pass A: bin edges by dst range into packed codes (src<<14 | dst_local) ----
__global__ void k_bin(const int* __restrict__ src, const int* __restrict__ dst,
                      int* __restrict__ bcur, unsigned* __restrict__ benc) {
    __shared__ int cnt[NB], base[NB], lcur[NB];
    int tid = threadIdx.x;
    if (tid < NB) cnt[tid] = 0;
    __syncthreads();
    const int4* s4 = (const int4*)src;
    const int4* d4 = (const int4*)dst;
    int i0 = blockIdx.x * (BIN_SEG / 4);
#pragma unroll
    for (int k = 0; k < 4; ++k) {
        int i4 = i0 + tid + k * 256;
        if (i4 < E4) {
            int4 dv = d4[i4];
            atomicAdd(&cnt[dv.x / BROW], 1);
            atomicAdd(&cnt[dv.y / BROW], 1);
            atomicAdd(&cnt[dv.z / BROW], 1);
            atomicAdd(&cnt[dv.w / BROW], 1);
        }
    }
    __syncthreads();
    if (tid < NB) { base[tid] = atomicAdd(&bcur[tid], cnt[tid]); lcur[tid] = 0; }
    __syncthreads();
#pragma unroll
    for (int k = 0; k < 4; ++k) {
        int i4 = i0 + tid + k * 256;
        if (i4 < E4) {
            int4 dv = d4[i4];
            int4 sv = s4[i4];
            int b; int p;
            b = dv.x / BROW; p = atomicAdd(&lcur[b], 1);
            benc[(long long)b * BCAP + base[b] + p] = ((unsigned)sv.x << 14) | (unsigned)(dv.x - b * BROW);
            b = dv.y / BROW; p = atomicAdd(&lcur[b], 1);
            benc[(long long)b * BCAP + base[b] + p] = ((unsigned)sv.y << 14) | (unsigned)(dv.y - b * BROW);
            b = dv.z / BROW; p = atomicAdd(&lcur[b], 1);
            benc[(long long)b * BCAP + base[b] + p] = ((unsigned)sv.z << 14) | (unsigned)(dv.z - b * BROW);
            b = dv.w / BROW; p = atomicAdd(&lcur[b], 1);
            benc[(long long)b * BCAP + base[b] + p] = ((unsigned)sv.w << 14) | (unsigned)(dv.w - b * BROW);
        }
    }
}

// ---- pass B: per-bucket degree histogram (bucket pinned to XCD via blockIdx&7) ----
__global__ void k_cnt2(const unsigned* __restrict__ benc, const int* __restrict__ bcur,
                       int* __restrict__ deg_i) {
    int bk = blockIdx.x & (NB - 1);
    int grp = blockIdx.x >> 3;
    int ngrp = gridDim.x >> 3;
    int cnt = bcur[bk];
    const unsigned* p = benc + (long long)bk * BCAP;
    int nb = bk * BROW;
    for (int i = grp * blockDim.x + threadIdx.x; i < cnt; i += ngrp * blockDim.x)
        atomicAdd(&deg_i[nb + (int)(p[i] & 0x3FFFu)], 1);
}

// per-block sums of 8-padded degrees
__global__ void k_bsum(const int* __restrict__ deg_i, int* __restrict__ bsum) {
    __shared__ int red[SCAN_BLK];
    int tid = threadIdx.x;
    int i = blockIdx.x * SCAN_BLK + tid;
    red[tid] = (i < N_NODES) ? ((deg_i[i] + 7) & ~7) : 0;
    __syncthreads();
    for (int s = SCAN_BLK / 2; s > 0; s >>= 1) {
        if (tid < s) red[tid] += red[tid + s];
        __syncthreads();
    }
    if (tid == 0) bsum[blockIdx.x] = red[0];
}

__global__ void k_bscan(const int* __restrict__ bsum, int* __restrict__ bscan) {
    __shared__ int sc[128];
    int tid = threadIdx.x;
    int v = (tid < SCAN_NB) ? bsum[tid] : 0;
    sc[tid] = v;
    __syncthreads();
    for (int off = 1; off < 128; off <<= 1) {
        int t = 0;
        if (tid >= off) t = sc[tid - off];
        __syncthreads();
        if (tid >= off) sc[tid] += t;
        __syncthreads();
    }
    if (tid < SCAN_NB) bscan[tid] = sc[tid] - v;
}

// per-block scan -> offsets/cursor; dis = rsqrt(deg+1); sx = x*dis fp16
__global__ void k_csr(const int* __restrict__ deg_i, const int* __restrict__ bscan,
                      const float* __restrict__ x,
                      int* __restrict__ offsets, int* __restrict__ cursor,
                      float* __restrict__ dis, f16* __restrict__ sx) {
    __shared__ int sc[SCAN_BLK];
    int tid = threadIdx.x;
    int i = blockIdx.x * SCAN_BLK + tid;
    int dv = (i < N_NODES) ? deg_i[i] : 0;
    int v = (i < N_NODES) ? ((dv + 7) & ~7) : 0;
    sc[tid] = v;
    __syncthreads();
    for (int off = 1; off < SCAN_BLK; off <<= 1) {
        int t = 0;
        if (tid >= off) t = sc[tid - off];
        __syncthreads();
        if (tid >= off) sc[tid] += t;
        __syncthreads();
    }
    int base = bscan[blockIdx.x];
    if (i < N_NODES) {
        int excl = base + sc[tid] - v;
        offsets[i] = excl;
        cursor[i] = excl;
        float dn = rsqrtf((float)(dv + 1));
        dis[i] = dn;
#pragma unroll
        for (int j = 0; j < IN_F; ++j)
            sx[i * SXS + j] = (f16)(x[i * IN_F + j] * dn);
        sx[i * SXS + 6] = (f16)0.0f;
        sx[i * SXS + 7] = (f16)0.0f;
        if (i == N_NODES - 1) offsets[N_NODES] = base + sc[tid];
    }
}

// ---- pass D: per-bucket CSR placement (XCD-pinned; dirty window ~1.8MB) ----
__global__ void k_place2(const unsigned* __restrict__ benc, const int* __restrict__ bcur,
                         int* __restrict__ cursor, int* __restrict__ csr_src) {
    int bk = blockIdx.x & (NB - 1);
    int grp = blockIdx.x >> 3;
    int ngrp = gridDim.x >> 3;
    int cnt = bcur[bk];
    const unsigned* p = benc + (long long)bk * BCAP;
    int nb = bk * BROW;
    for (int i = grp * blockDim.x + threadIdx.x; i < cnt; i += ngrp * blockDim.x) {
        unsigned e = p[i];
        int d = nb + (int)(e & 0x3FFFu);
        int s = (int)(e >> 14);
        csr_src[atomicAdd(&cursor[d], 1)] = s;
    }
}

// fill pad slots with the zero-row index N_NODES
__global__ void k_pad(const int* __restrict__ offsets, const int* __restrict__ cursor,
                      int* __restrict__ csr_src) {
    int i = blockIdx.x * blockDim.x + threadIdx.x;
    if (i >= N_NODES) return;
    int e = offsets[i + 1];
    for (int j = cursor[i]; j < e; ++j) csr_src[j] = N_NODES;
}

// aggx[n,f] = sx[n,f] + sum over incoming neighbors; 8 lanes/node, unroll x8
__global__ void k_gather1(const f16* __restrict__ sx, const int* __restrict__ offsets,
                          const int* __restrict__ csr_src, float* __restrict__ aggx) {
    int idx = blockIdx.x * blockDim.x + threadIdx.x;
    if (idx >= N_NODES * 8) return;
    int n = idx >> 3;
    int f = idx & 7;
    float acc = (float)sx[(n << 3) + f];
    int b = offsets[n], e = offsets[n + 1];
    for (int j = b; j < e; j += 8) {
        const int4* p = (const int4*)(csr_src + j);
        int4 ia = p[0], ib = p[1];
        float v0 = (float)sx[(ia.x << 3) + f], v1 = (float)sx[(ia.y << 3) + f];
        float v2 = (float)sx[(ia.z << 3) + f], v3 = (float)sx[(ia.w << 3) + f];
        float v4 = (float)sx[(ib.x << 3) + f], v5 = (float)sx[(ib.y << 3) + f];
        float v6 = (float)sx[(ib.z << 3) + f], v7 = (float)sx[(ib.w << 3) + f];
        acc += ((v0 + v1) + (v2 + v3)) + ((v4 + v5) + (v6 + v7));
    }
    aggx[(n << 3) + f] = acc;
}

// fused: h1 = lrelu(dis*(aggx@W1)+b1) (LDS only), t2 = dis*(h1@W2) in fp16
__global__ void k_h1t2(const float* __restrict__ aggx, const float* __restrict__ W1,
                       const float* __restrict__ b1, const float* __restrict__ W2,
                       const float* __restrict__ dis, f16* __restrict__ t2) {
    __shared__ float sW1[IN_F * H1];
    __shared__ float sb1[H1];
    __shared__ float sW2[H1 * H2];
    __shared__ float sh1[8][H1];
    int tid = threadIdx.x;
    for (int i = tid; i < IN_F * H1; i += 256) sW1[i] = W1[i];
    if (tid < H1) sb1[tid] = b1[tid];
    for (int i = tid; i < H1 * H2; i += 256) sW2[i] = W2[i];
    int loc = tid >> 5;
    int lane = tid & 31;
    int n = blockIdx.x * 8 + loc;
    bool ok = n < N_NODES;
    float a[IN_F];
    float dn = 0.0f;
    if (ok) {
        dn = dis[n];
#pragma unroll
        for (int j = 0; j < IN_F; ++j) a[j] = aggx[n * SXS + j];
    }
    __syncthreads();
    if (ok) {
#pragma unroll
        for (int kk = 0; kk < 2; ++kk) {
            int k = lane + kk * 32;
            float s = 0.0f;
#pragma unroll
            for (int j = 0; j < IN_F; ++j) s += a[j] * sW1[j * H1 + k];
            sh1[loc][k] = lrelu(s * dn + sb1[k]);
        }
    }
    __syncthreads();
    if (ok) {
        float s = 0.0f;
#pragma unroll
        for (int k = 0; k < H1; ++k) s += sh1[loc][k] * sW2[k * H2 + lane];
        t2[n * H2 + lane] = (f16)(s * dn);
    }
}

// agg2 gather (unroll x16) + lrelu + LDS-deduped mean-pool accumulation
__global__ void k_gather2(const f16* __restrict__ t2, const int* __restrict__ offsets,
                          const int* __restrict__ csr_src, const float* __restrict__ dis,
                          const float* __restrict__ b2, const int* __restrict__ batch,
                          float* __restrict__ gsum, float* __restrict__ gcnt) {
    __shared__ float sv[8][H2];
    __shared__ int sg[8];
    int idx = blockIdx.x * blockDim.x + threadIdx.x;
    int n = idx >> 5;
    int f = idx & 31;
    float acc = (float)t2[(n << 5) + f];
    int b = offsets[n], e = offsets[n + 1];
    int j = b;
    for (; j + 16 <= e; j += 16) {
        const int4* p = (const int4*)(csr_src + j);
        int4 ia = p[0], ib = p[1], ic = p[2], id = p[3];
        float v0 = (float)t2[(ia.x << 5) + f], v1 = (float)t2[(ia.y << 5) + f];
        float v2 = (float)t2[(ia.z << 5) + f], v3 = (float)t2[(ia.w << 5) + f];
        float v4 = (float)t2[(ib.x << 5) + f], v5 = (float)t2[(ib.y << 5) + f];
        float v6 = (float)t2[(ib.z << 5) + f], v7 = (float)t2[(ib.w << 5) + f];
        float v8 = (float)t2[(ic.x << 5) + f], v9 = (float)t2[(ic.y << 5) + f];
        float va = (float)t2[(ic.z << 5) + f], vb = (float)t2[(ic.w << 5) + f];
        float vc = (float)t2[(id.x << 5) + f], vd = (float)t2[(id.y << 5) + f];
        float ve = (float)t2[(id.z << 5) + f], vf = (float)t2[(id.w << 5) + f];
        acc += (((v0 + v1) + (v2 + v3)) + ((v4 + v5) + (v6 + v7)))
             + (((v8 + v9) + (va + vb)) + ((vc + vd) + (ve + vf)));
    }
    if (j < e) {
        const int4* p = (const int4*)(csr_src + j);
        int4 ia = p[0], ib = p[1];
        float v0 = (float)t2[(ia.x << 5) + f], v1 = (float)t2[(ia.y << 5) + f];
        float v2 = (float)t2[(ia.z << 5) + f], v3 = (float)t2[(ia.w << 5) + f];
        float v4 = (float)t2[(ib.x << 5) + f], v5 = (float)t2[(ib.y << 5) + f];
        float v6 = (float)t2[(ib.z << 5) + f], v7 = (float)t2[(ib.w << 5) + f];
        acc += ((v0 + v1) + (v2 + v3)) + ((v4 + v5) + (v6 + v7));
    }
    float v = lrelu(acc * dis[n] + b2[f]);
    int g = batch[n];
    int loc = threadIdx.x >> 5;
    sv[loc][f] = v;
    if (f == 0) sg[loc] = g;
    __syncthreads();
    bool leader = true;
    for (int l = 0; l < loc; ++l) leader &= (sg[l] != g);
    if (leader) {
        float s = v;
        float c = 1.0f;
        for (int l = loc + 1; l < 8; ++l)
            if (sg[l] == g) { s += sv[l][f]; c += 1.0f; }
        atomicAdd(&gsum[g * H2 + f], s);
        if (f == 0) atomicAdd(&gcnt[g], c);
    }
}

__global__ void k_final(const float* __restrict__ gsum, const float* __restrict__ gcnt,
                        const float* __restrict__ Wlin, const float* __restrict__ blin,
                        float* __restrict__ out) {
    int idx = blockIdx.x * blockDim.x + threadIdx.x;
    if (idx >= N_GRAPHS * 2) return;
    int g = idx >> 1;
    int t = idx & 1;
    float inv = 1.0f / fmaxf(gcnt[g], 1.0f);
    float s = blin[t];
#pragma unroll
    for (int f = 0; f < H2; ++f)
        s += gsum[g * H2 + f] * inv * Wlin[f * 2 + t];
    out[idx] = s;
}

static inline int cdiv(long long a, int b) { return (int)((a + b - 1) / b); }

extern "C" void kernel_launch(void* const* d_in, const int* in_sizes, int n_in,
                              void* d_out, int out_size, void* d_ws, size_t ws_size,
                              hipStream_t stream) {
    const float* x    = (const float*)d_in[0];
    const int*   ei   = (const int*)d_in[1];
    const int*   batch= (const int*)d_in[2];
    const float* W1   = (const float*)d_in[3];
    const float* b1   = (const float*)d_in[4];
    const float* W2   = (const float*)d_in[5];
    const float* b2   = (const float*)d_in[6];
    const float* Wlin = (const float*)d_in[7];
    const float* blin = (const float*)d_in[8];
    float* out = (float*)d_out;

    const int* src = ei;
    const int* dst = ei + N_EDGES;

    // ---- workspace layout ----
    f16*   t2   = (f16*)d_ws;                           // 32*(N+1)
    f16*   sx   = t2 + 32LL * (N_NODES + 1);            // 8*(N+1)
    float* dis  = (float*)(sx + 8LL * (N_NODES + 1));   // N
    float* aggx = dis + N_NODES;                        // 8N
    float* gsum = aggx + 8LL * N_NODES;                 // 32G
    float* gcnt = gsum + (long long)N_GRAPHS * H2;      // G
    size_t ioff = ((size_t)(gcnt + N_GRAPHS) + 15) & ~(size_t)15;
    int*  csr_src = (int*)ioff;                         // CSR_CAP
    int*  deg_i   = csr_src + CSR_CAP;                  // N
    int*  offsets = deg_i + N_NODES;                    // N+1
    int*  cursor  = offsets + N_NODES + 1;              // N
    int*  bsum    = cursor + N_NODES;                   // 128
    int*  bscan   = bsum + 128;                         // 128
    int*  bcur    = bscan + 128;                        // NB
    unsigned* benc = (unsigned*)(bcur + NB);            // NB*BCAP

    const int B = 256;

    hipMemsetAsync(deg_i, 0, sizeof(int) * N_NODES, stream);
    hipMemsetAsync(gsum, 0, sizeof(float) * (N_GRAPHS * H2 + N_GRAPHS), stream);
    hipMemsetAsync(bcur, 0, sizeof(int) * NB, stream);
    hipMemsetAsync(t2 + 32LL * N_NODES, 0, 32 * sizeof(f16), stream);  // zero row
    hipMemsetAsync(sx + 8LL * N_NODES, 0, 8 * sizeof(f16), stream);    // zero row

    k_bin<<<cdiv(N_EDGES, BIN_SEG), B, 0, stream>>>(src, dst, bcur, benc);
    k_cnt2<<<1024, B, 0, stream>>>(benc, bcur, deg_i);
    k_bsum<<<SCAN_NB, SCAN_BLK, 0, stream>>>(deg_i, bsum);
    k_bscan<<<1, 128, 0, stream>>>(bsum, bscan);
    k_csr<<<SCAN_NB, SCAN_BLK, 0, stream>>>(deg_i, bscan, x, offsets, cursor, dis, sx);
    k_place2<<<1024, B, 0, stream>>>(benc, bcur, cursor, csr_src);
    k_pad<<<cdiv(N_NODES, B), B, 0, stream>>>(offsets, cursor, csr_src);

    k_gather1<<<cdiv((long long)N_NODES * 8, B), B, 0, stream>>>(sx, offsets, csr_src, aggx);
    k_h1t2<<<cdiv(N_NODES, 8), B, 0, stream>>>(aggx, W1, b1, W2, dis, t2);
    k_gather2<<<cdiv((long long)N_NODES * H2, B), B, 0, stream>>>(t2, offsets, csr_src, dis,
                                                                  b2, batch, gsum, gcnt);
    k_final<<<cdiv(N_GRAPHS * 2, B), B, 0, stream>>>(gsum, gcnt, Wlin, blin, out);
}